// Round 6
// baseline (139.810 us; speedup 1.0000x reference)
//
#include <hip/hip_runtime.h>
#include <hip/hip_bf16.h>
#include <stdint.h>

#define B_  64
#define N_  576
#define D_  1024
#define K_  144
#define HW_ 24
#define DIST_THR_F 16.733200530681511f

using bf16x8 = __attribute__((ext_vector_type(8))) short;
using f32x4  = __attribute__((ext_vector_type(4))) float;

__device__ __forceinline__ unsigned short f2bf(float f) {
    unsigned u = __float_as_uint(f);
    u += 0x7fffu + ((u >> 16) & 1u);
    return (unsigned short)(u >> 16);
}

// ---------------- Kernel 1: token selection (one block per batch) ----------------
// Also zeroes the per-row weight-sum accumulator for this batch (graph-replay safe).
__global__ __launch_bounds__(256) void k_select(const float* __restrict__ metric,
                                                int* __restrict__ bench_idx,
                                                int* __restrict__ high,
                                                float* __restrict__ out_idx,
                                                float* __restrict__ rowsum) {
    __shared__ float sm[N_];
    __shared__ float sc[512];
    __shared__ int   si[512];
    __shared__ unsigned smask[18];
    __shared__ int   wpref[18];
    __shared__ float thr_s;
    int b = blockIdx.x, tid = threadIdx.x;
    for (int i = tid; i < N_; i += 256) sm[i] = metric[b * N_ + i];
    if (tid < 18) smask[tid] = 0u;
    if (tid < 144) rowsum[b * K_ + tid] = 0.f;
    __syncthreads();
    if (tid < 144) {
        int ry = tid / 12, rx = tid - ry * 12;
        int base = ry * 48 + rx * 2;
        float vv[4] = { sm[base], sm[base + 1], sm[base + 24], sm[base + 25] };
        int   tk[4] = { base, base + 1, base + 24, base + 25 };
        int a0 = 0;
#pragma unroll
        for (int j = 1; j < 4; j++) if (vv[j] > vv[a0]) a0 = j;
        int a1 = -1;
#pragma unroll
        for (int j = 0; j < 4; j++) {
            if (j == a0) continue;
            if (a1 < 0 || vv[j] > vv[a1]) a1 = j;
        }
        sc[2 * tid]     = vv[a0]; si[2 * tid]     = tk[a0];
        sc[2 * tid + 1] = vv[a1]; si[2 * tid + 1] = tk[a1];
    }
    for (int i = 288 + tid; i < 512; i += 256) { sc[i] = -1e30f; si[i] = 0x7fffffff; }
    __syncthreads();
    for (int k = 2; k <= 512; k <<= 1) {
        for (int j = k >> 1; j > 0; j >>= 1) {
#pragma unroll 2
            for (int t = tid; t < 512; t += 256) {
                int ixj = t ^ j;
                if (ixj > t) {
                    float s1 = sc[t], s2 = sc[ixj];
                    int   i1 = si[t], i2 = si[ixj];
                    bool before = (s1 > s2) || (s1 == s2 && i1 < i2);
                    bool up = ((t & k) == 0);
                    if (up ? !before : before) {
                        sc[t] = s2; sc[ixj] = s1; si[t] = i2; si[ixj] = i1;
                    }
                }
            }
            __syncthreads();
        }
    }
    if (tid == 0) {
        float qpos = 0.55f * 143.0f;
        float g = qpos - 78.0f;
        thr_s = sc[65] * (1.0f - g) + sc[64] * g;
    }
    if (tid < 144) atomicOr(&smask[si[tid] >> 5], 1u << (si[tid] & 31));
    __syncthreads();
    if (tid == 0) {
        int acc = 0;
        for (int w = 0; w < 18; w++) { wpref[w] = acc; acc += __popc(smask[w]); }
    }
    __syncthreads();
    if (tid < 144) {
        int tok = si[tid], w = tok >> 5;
        int rank = wpref[w] + __popc(smask[w] & ((1u << (tok & 31)) - 1u));
        bench_idx[b * K_ + rank] = tok;
        high[b * K_ + rank] = (sc[tid] >= thr_s) ? 1 : 0;
        out_idx[b * K_ + rank] = (float)tok;
    }
}

// ---------------- Kernel 2: fused normalize + sim GEMM + penalty -> bwn -------------
// block = (b, ct in 0..2): 144 bench rows x 192 cols. 384 thr / 6 waves (3x2).
// COALESCED staging: one wave-load = 2 rows x 32 lanes x float2 = full BK=64 K-tile
// of 2 rows. Row (j, halfwave): row = j*12 + w*2 + hl; j<12 -> A (gathered bench
// tokens), j>=12 -> B (contiguous tokens ct*192+row-144). Per-lane ss partials
// reduced over the 32 lanes of a row via shfl (no atomics). launch_bounds(384,1)
// to avoid the VGPR squeeze that spilled k_sim5 (108 regs vs ~150 live).
__global__ __launch_bounds__(384, 1) void k_sim6(const float* __restrict__ hs,
                                                 const int* __restrict__ bench_idx,
                                                 const int* __restrict__ high,
                                                 unsigned short* __restrict__ bwn,
                                                 float* __restrict__ rowsum) {
    __shared__ unsigned short SM[336 * 64];
    __shared__ float ssL[336];
    __shared__ float rsum[144];
    unsigned* SM32 = reinterpret_cast<unsigned*>(SM);

    int bid  = blockIdx.x;
    int xcd  = bid & 7;
    int slot = bid >> 3;               // 0..23
    int ct   = slot % 3;
    int b    = (slot / 3) * 8 + xcd;
    int tid  = threadIdx.x;
    int w = tid >> 6, lane = tid & 63, g = lane >> 4, r16 = lane & 15;
    int wr = w >> 1, wc = w & 1;       // 3x2 wave grid: rows wr*48, cols wc*96
    int hl  = lane >> 5;               // half-wave
    int l31 = lane & 31;

    if (tid < 144) rsum[tid] = 0.f;

    const float* base = hs + (size_t)b * N_ * D_;
    int c = w * 2 + hl;                // row offset within j-group (0..11)

    // A-row token gather (rows 0..143 = j*12 + c, j<12)
    int voffA[12];
#pragma unroll
    for (int j = 0; j < 12; j++) {
        int tok = bench_idx[b * K_ + j * 12 + c];
        voffA[j] = tok * D_ + l31 * 2;
    }
    // B rows: token = ct*192 + (row-144), row = j*12 + c, j>=12
    const float* baseB = base + ((long)(ct * 192 - 144 + c) * D_ + l31 * 2);

    // ds_write offsets: word index = row*32 + ((s ^ (row&7))<<2) + (l31&3), s = l31>>2
    int dsbase = c * 32 + (l31 & 3);
    int sw0 = ((l31 >> 2) ^ (c & 7)) << 2;           // j even: row&7 = c&7
    int sw1 = ((l31 >> 2) ^ ((c + 4) & 7)) << 2;     // j odd:  row&7 = (c+4)&7

    float2 fd[28];
    float  ssp[28];
#pragma unroll
    for (int j = 0; j < 28; j++) ssp[j] = 0.f;

    // prologue: loads for t=0
#pragma unroll
    for (int j = 0; j < 12; j++) fd[j] = *(const float2*)(base + voffA[j]);
#pragma unroll
    for (int j = 12; j < 28; j++) fd[j] = *(const float2*)(baseB + j * 12 * D_);

    f32x4 acc[3][6] = {};

    for (int t = 0; t < 16; ++t) {
        // ---- pack + ds_write tile t ----
#pragma unroll
        for (int j = 0; j < 28; j++) {
            float x = fd[j].x, y = fd[j].y;
            ssp[j] += x * x + y * y;
            unsigned pk = (unsigned)f2bf(x) | ((unsigned)f2bf(y) << 16);
            SM32[dsbase + j * 384 + ((j & 1) ? sw1 : sw0)] = pk;
        }
        __syncthreads();
        // ---- issue next-tile loads (fly under MFMA) ----
        if (t < 15) {
            int koff = (t + 1) * 64;
#pragma unroll
            for (int j = 0; j < 12; j++) fd[j] = *(const float2*)(base + voffA[j] + koff);
#pragma unroll
            for (int j = 12; j < 28; j++) fd[j] = *(const float2*)(baseB + j * 12 * D_ + koff);
        }
        // ---- MFMA phase ----
#pragma unroll
        for (int h = 0; h < 2; h++) {
            int ks = h * 4 + g;
            bf16x8 af[3], bf[6];
#pragma unroll
            for (int mi = 0; mi < 3; mi++) {
                int row = wr * 48 + mi * 16 + r16;
                af[mi] = *(const bf16x8*)&SM[row * 64 + (ks ^ (row & 7)) * 8];
            }
#pragma unroll
            for (int nj = 0; nj < 6; nj++) {
                int row = 144 + wc * 96 + nj * 16 + r16;
                bf[nj] = *(const bf16x8*)&SM[row * 64 + (ks ^ (row & 7)) * 8];
            }
#pragma unroll
            for (int mi = 0; mi < 3; mi++)
#pragma unroll
                for (int nj = 0; nj < 6; nj++)
                    acc[mi][nj] = __builtin_amdgcn_mfma_f32_16x16x32_bf16(af[mi], bf[nj], acc[mi][nj], 0, 0, 0);
        }
        __syncthreads();
    }

    // ---- per-row sum(x^2): reduce over the 32 lanes sharing each row, plain write ----
#pragma unroll
    for (int j = 0; j < 28; j++) {
        float s = ssp[j];
#pragma unroll
        for (int m = 1; m <= 16; m <<= 1) s += __shfl_xor(s, m, 64);
        if (l31 == 0) ssL[j * 12 + c] = s;
    }
    __syncthreads();

    // ---- epilogue: val = relu(acc)*invA*invB*pen; row-sum; write (self=0, high=0) ----
    float invB6[6];
#pragma unroll
    for (int nj = 0; nj < 6; nj++)
        invB6[nj] = 1.0f / fmaxf(sqrtf(ssL[144 + wc * 96 + nj * 16 + r16]), 1e-12f);
#pragma unroll
    for (int mi = 0; mi < 3; mi++) {
#pragma unroll
        for (int r = 0; r < 4; r++) {
            int i = wr * 48 + mi * 16 + g * 4 + r;
            int ti = bench_idx[b * K_ + i];
            int hi = high[b * K_ + i];
            float invA = 1.0f / fmaxf(sqrtf(ssL[i]), 1e-12f);
            int y1 = ti / HW_, x1 = ti % HW_;
            unsigned short* prow = bwn + (size_t)(b * K_ + i) * N_;
            float sum6 = 0.f;
            float vals[6];
#pragma unroll
            for (int nj = 0; nj < 6; nj++) {
                int col = ct * 192 + wc * 96 + nj * 16 + r16;
                int y2 = col / HW_, x2 = col % HW_;
                float dy = (float)(y1 - y2), dx = (float)(x1 - x2);
                float dist = sqrtf(dy * dy + dx * dx);
                float pen = 1.0f - fminf(dist / DIST_THR_F, 1.0f);
                float v = fmaxf(acc[mi][nj][r], 0.0f) * invA * invB6[nj] * pen;
                vals[nj] = v;
                sum6 += v;
            }
#pragma unroll
            for (int m = 1; m <= 8; m <<= 1) sum6 += __shfl_xor(sum6, m, 64);
            if (r16 == 0) atomicAdd(&rsum[i], sum6);
#pragma unroll
            for (int nj = 0; nj < 6; nj++) {
                int col = ct * 192 + wc * 96 + nj * 16 + r16;
                unsigned short o = (hi || col == ti) ? (unsigned short)0 : f2bf(vals[nj]);
                prow[col] = o;
            }
        }
    }
    __syncthreads();
    if (tid < 144) atomicAdd(&rowsum[b * K_ + tid], rsum[tid]);
}

// ---------------- Kernel 3: aggregation GEMM, fused transpose + normalize + self ----
// (unchanged from round 5 — measured at HBM roofline ~28 us)
__global__ __launch_bounds__(384) void k_agg5(const unsigned short* __restrict__ bwn,
                                              const float* __restrict__ agg,
                                              const int* __restrict__ bench_idx,
                                              const float* __restrict__ rowsum,
                                              float* __restrict__ out) {
    __shared__ unsigned short LA[144 * 64];
    __shared__ unsigned int   LB[256 * 32];     // [d][32 u32 of j-pairs]
    int bid  = blockIdx.x;
    int xcd  = bid & 7;
    int s    = bid >> 3;               // 0..31
    int dt   = s & 3;
    int b    = (s >> 2) * 8 + xcd;
    int tid  = threadIdx.x;
    int w = tid >> 6, lane = tid & 63, g = lane >> 4, r16 = lane & 15;
    int wr = w >> 1, wc = w & 1;       // rows wr*48, d-cols wc*128

    const unsigned short* asrc[3];
    int adso[3];
#pragma unroll
    for (int q = 0; q < 3; q++) {
        int cid = tid + 384 * q;
        int row = cid >> 3, p = cid & 7, l = p ^ (row & 7);
        asrc[q] = bwn + (size_t)(b * K_ + row) * N_ + l * 8;
        adso[q] = row * 64 + p * 8;
    }
    const float* bbase = agg + (size_t)b * N_ * D_ + dt * 256 + lane * 4;

    bf16x8 areg[3];
    float4 breg[6][2];
#pragma unroll
    for (int q = 0; q < 3; q++) areg[q] = *(const bf16x8*)(asrc[q]);
#pragma unroll
    for (int u = 0; u < 6; u++) {
        int pp = w + 6 * u;
        if (pp < 32) {
            breg[u][0] = *(const float4*)(bbase + (size_t)(2 * pp) * D_);
            breg[u][1] = *(const float4*)(bbase + (size_t)(2 * pp + 1) * D_);
        }
    }

    f32x4 acc[3][8] = {};

    for (int t = 0; t < 9; ++t) {
#pragma unroll
        for (int q = 0; q < 3; q++) *(bf16x8*)&LA[adso[q]] = areg[q];
#pragma unroll
        for (int u = 0; u < 6; u++) {
            int pp = w + 6 * u;
            if (pp < 32) {
                float a0[4] = { breg[u][0].x, breg[u][0].y, breg[u][0].z, breg[u][0].w };
                float a1[4] = { breg[u][1].x, breg[u][1].y, breg[u][1].z, breg[u][1].w };
                int js = pp >> 2;
#pragma unroll
                for (int c = 0; c < 4; c++) {
                    int d = lane * 4 + c;
                    int sw = (js ^ (d & 7) ^ ((d >> 3) & 7)) & 7;
                    unsigned pk = (unsigned)f2bf(a0[c]) | ((unsigned)f2bf(a1[c]) << 16);
                    LB[d * 32 + sw * 4 + (pp & 3)] = pk;
                }
            }
        }
        __syncthreads();
        if (t < 8) {
            int kb = (t + 1) * 64;
#pragma unroll
            for (int q = 0; q < 3; q++) areg[q] = *(const bf16x8*)(asrc[q] + kb);
#pragma unroll
            for (int u = 0; u < 6; u++) {
                int pp = w + 6 * u;
                if (pp < 32) {
                    breg[u][0] = *(const float4*)(bbase + (size_t)(kb + 2 * pp) * D_);
                    breg[u][1] = *(const float4*)(bbase + (size_t)(kb + 2 * pp + 1) * D_);
                }
            }
        }
#pragma unroll
        for (int h = 0; h < 2; h++) {
            int ks = h * 4 + g;
            bf16x8 af[3], bf[8];
#pragma unroll
            for (int mi = 0; mi < 3; mi++) {
                int row = wr * 48 + mi * 16 + r16;
                af[mi] = *(const bf16x8*)&LA[row * 64 + (ks ^ (row & 7)) * 8];
            }
#pragma unroll
            for (int nj = 0; nj < 8; nj++) {
                int d = wc * 128 + nj * 16 + r16;
                int sw = (ks ^ (d & 7) ^ ((d >> 3) & 7)) & 7;
                bf[nj] = *(const bf16x8*)&LB[d * 32 + sw * 4];
            }
#pragma unroll
            for (int mi = 0; mi < 3; mi++)
#pragma unroll
                for (int nj = 0; nj < 8; nj++)
                    acc[mi][nj] = __builtin_amdgcn_mfma_f32_16x16x32_bf16(af[mi], bf[nj], acc[mi][nj], 0, 0, 0);
        }
        __syncthreads();
    }

    // epilogue: normalize by S' and add self row (exact f32)
#pragma unroll
    for (int mi = 0; mi < 3; mi++) {
#pragma unroll
        for (int r = 0; r < 4; r++) {
            int i = wr * 48 + mi * 16 + g * 4 + r;
            float S = rowsum[b * K_ + i];
            float sc = 1.0f / (S + 1e-8f);
            int ti = bench_idx[b * K_ + i];
            const float* selfrow = agg + (size_t)(b * N_ + ti) * D_ + dt * 256 + wc * 128;
            float* orow = out + (size_t)(b * K_ + i) * D_ + dt * 256 + wc * 128;
#pragma unroll
            for (int nj = 0; nj < 8; nj++)
                orow[nj * 16 + r16] = acc[mi][nj][r] * sc + selfrow[nj * 16 + r16];
        }
    }
}

extern "C" void kernel_launch(void* const* d_in, const int* in_sizes, int n_in,
                              void* d_out, int out_size, void* d_ws, size_t ws_size,
                              hipStream_t stream) {
    const float* hs_agg = (const float*)d_in[0];
    const float* hs_sim = (const float*)d_in[1];
    const float* metric = (const float*)d_in[2];
    float* out = (float*)d_out;
    char* ws = (char*)d_ws;

    const size_t BWN_BYTES = (size_t)B_ * K_ * N_ * 2;    // 10,616,832
    unsigned short* bwn = (unsigned short*)ws;
    int*   bench_idx = (int*)(ws + BWN_BYTES);
    int*   high      = (int*)(ws + BWN_BYTES + (size_t)B_ * K_ * 4);
    float* rowsum    = (float*)(ws + BWN_BYTES + (size_t)B_ * K_ * 8);
    float* out_idx   = out + (size_t)B_ * K_ * D_;

    hipLaunchKernelGGL(k_select, dim3(B_),     dim3(256), 0, stream, metric, bench_idx, high, out_idx, rowsum);
    hipLaunchKernelGGL(k_sim6,   dim3(B_ * 3), dim3(384), 0, stream, hs_sim, bench_idx, high, bwn, rowsum);
    hipLaunchKernelGGL(k_agg5,   dim3(B_ * 4), dim3(384), 0, stream, bwn, hs_agg, bench_idx, rowsum, out);
}